// Round 1
// baseline (6465.659 us; speedup 1.0000x reference)
//
#include <hip/hip_runtime.h>

// Pool_FPS: furthest point sampling (B=8, N=32768, K=1024) + gather (C=128).
// FPS kernel: 1 block per batch, 512 threads, 64 pts/thread.
//  - x,y,dists in VGPRs; z in dynamic LDS (128KB).
//  - exact fp32 arithmetic matching numpy/jax: d = ((dx*dx + dy*dy) + dz*dz)
//    with rn ops (no contraction); argmax tie-break = smallest index.
// Gather kernel: one thread per output element.

#define BATCH 8
#define NPTS 32768
#define KSEL 1024
#define CFEAT 128
#define TPB 512
#define PT (NPTS / TPB)   // 64 points per thread
#define NWAVE (TPB / 64)  // 8 waves

__launch_bounds__(TPB, 2)
__global__ void fps_kernel(const float* __restrict__ xyz, int* __restrict__ idxbuf) {
    extern __shared__ float smem[];
    float* zsh    = smem;                        // [NPTS]
    float* sred_d = smem + NPTS;                 // [NWAVE]
    int*   sred_n = (int*)(smem + NPTS + NWAVE); // [NWAVE]
    float* sc     = smem + NPTS + 2 * NWAVE;     // [3]: cx, cy, cz

    const int b   = blockIdx.x;
    const int tid = threadIdx.x;
    const float* Xp = xyz + (size_t)b * 3 * NPTS;
    const float* Yp = Xp + NPTS;
    const float* Zp = Xp + 2 * NPTS;

    float xs[PT], ys[PT], ds[PT];
#pragma unroll
    for (int j = 0; j < PT; ++j) {
        const int n = tid + j * TPB;
        xs[j] = Xp[n];
        ys[j] = Yp[n];
        zsh[n] = Zp[n];
        ds[j] = INFINITY;
    }
    if (tid == 0) {
        sc[0] = Xp[0]; sc[1] = Yp[0]; sc[2] = Zp[0];
        idxbuf[(size_t)b * KSEL] = 0;  // idx[0] = 0 (FPS starts at point 0)
    }
    __syncthreads();

    const int lane = tid & 63;
    const int wid  = tid >> 6;

    for (int t = 1; t < KSEL; ++t) {
        const float cx = sc[0], cy = sc[1], cz = sc[2];
        float bd = -INFINITY;
        int   bn = 0;
#pragma unroll
        for (int j = 0; j < PT; ++j) {
            const int n = tid + j * TPB;
            const float dx = xs[j] - cx;
            const float dy = ys[j] - cy;
            const float dz = zsh[n] - cz;
            // exact: ((dx*dx + dy*dy) + dz*dz), rn, no fma contraction
            const float d = __fadd_rn(__fadd_rn(__fmul_rn(dx, dx), __fmul_rn(dy, dy)),
                                      __fmul_rn(dz, dz));
            const float nd = fminf(ds[j], d);
            ds[j] = nd;
            // strict > keeps the smallest n within this thread (j ascending => n ascending)
            const bool gt = nd > bd;
            bd = gt ? nd : bd;
            bn = gt ? n : bn;
        }
        // wave-level argmax reduce: max value, tie -> min index
#pragma unroll
        for (int off = 32; off >= 1; off >>= 1) {
            const float od = __shfl_xor(bd, off);
            const int   on = __shfl_xor(bn, off);
            if (od > bd || (od == bd && on < bn)) { bd = od; bn = on; }
        }
        if (lane == 0) { sred_d[wid] = bd; sred_n[wid] = bn; }
        __syncthreads();
        if (tid < 64) {
            float rd = (lane < NWAVE) ? sred_d[lane] : -INFINITY;
            int   rn = (lane < NWAVE) ? sred_n[lane] : 0x7FFFFFFF;
#pragma unroll
            for (int off = 4; off >= 1; off >>= 1) {
                const float od = __shfl_xor(rd, off);
                const int   on = __shfl_xor(rn, off);
                if (od > rd || (od == rd && on < rn)) { rd = od; rn = on; }
            }
            if (lane == 0) {
                idxbuf[(size_t)b * KSEL + t] = rn;
                sc[0] = Xp[rn]; sc[1] = Yp[rn]; sc[2] = Zp[rn];  // L2-resident fetch
            }
        }
        __syncthreads();
    }
}

__global__ void gather_kernel(const float* __restrict__ xyz,
                              const float* __restrict__ feat,
                              const int* __restrict__ idxbuf,
                              float* __restrict__ out) {
    const int SN = BATCH * 3 * KSEL;                  // 24576
    const int total = SN + BATCH * CFEAT * KSEL;      // 1073152
    const int i = blockIdx.x * blockDim.x + threadIdx.x;
    if (i >= total) return;
    if (i < SN) {
        const int b = i / (3 * KSEL);
        const int r = i - b * 3 * KSEL;
        const int c = r / KSEL;
        const int k = r - c * KSEL;
        const int n = idxbuf[b * KSEL + k];
        out[i] = xyz[((size_t)b * 3 + c) * NPTS + n];
    } else {
        const int i2 = i - SN;
        const int b = i2 / (CFEAT * KSEL);
        const int r = i2 - b * CFEAT * KSEL;
        const int c = r / KSEL;
        const int k = r - c * KSEL;
        const int n = idxbuf[b * KSEL + k];
        out[SN + i2] = feat[((size_t)b * CFEAT + c) * NPTS + n];
    }
}

extern "C" void kernel_launch(void* const* d_in, const int* in_sizes, int n_in,
                              void* d_out, int out_size, void* d_ws, size_t ws_size,
                              hipStream_t stream) {
    const float* xyz  = (const float*)d_in[0];
    const float* feat = (const float*)d_in[1];
    float* out = (float*)d_out;
    int* idxbuf = (int*)d_ws;  // BATCH*KSEL ints = 32KB

    const size_t smem_bytes = (size_t)(NPTS + 2 * NWAVE + 4) * sizeof(float);  // ~128KB
    hipFuncSetAttribute((const void*)fps_kernel,
                        hipFuncAttributeMaxDynamicSharedMemorySize, (int)smem_bytes);

    fps_kernel<<<BATCH, TPB, smem_bytes, stream>>>(xyz, idxbuf);

    const int total = BATCH * 3 * KSEL + BATCH * CFEAT * KSEL;  // 1073152
    gather_kernel<<<(total + 255) / 256, 256, 0, stream>>>(xyz, feat, idxbuf, out);
}

// Round 2
// 4908.801 us; speedup vs baseline: 1.3172x; 1.3172x over previous
//
#include <hip/hip_runtime.h>

// Pool_FPS: furthest point sampling (B=8, N=32768, K=1024) + gather (C=128).
// FPS kernel: 1 block per batch, 512 threads, 64 pts/thread (interleaved).
//  - x,y,dists in VGPRs (192 regs); z in dynamic LDS (128KB).
//  - __launch_bounds__(512, 1): 1 block/CU -> 256-VGPR cap -> NO SPILL
//    (round-0 used (512,2) which capped VGPRs at 128 and spilled ds[] to
//    scratch: 6.5ms. VGPR_Count must read ~210+ this round.)
//  - single barrier per iteration: wave argmax -> LDS (parity double-buffered)
//    -> syncthreads -> all threads redundantly reduce 8 wave slots.
//  - center coords re-fetched via readfirstlane + scalar loads (L2-resident).
//  - exact fp32 arithmetic matching numpy/jax: d = ((dx*dx + dy*dy) + dz*dz),
//    rn ops, no fma contraction; argmax tie-break = smallest index.
// Gather kernel: one thread per output element.

#define BATCH 8
#define NPTS 32768
#define KSEL 1024
#define CFEAT 128
#define TPB 512
#define PT (NPTS / TPB)   // 64 points per thread
#define NWAVE (TPB / 64)  // 8 waves

__launch_bounds__(TPB, 1)
__global__ void fps_kernel(const float* __restrict__ xyz, int* __restrict__ idxbuf) {
    extern __shared__ float smem[];
    float* zsh = smem;                       // [NPTS] 128KB
    float* sd  = smem + NPTS;                // [2][NWAVE] parity-buffered wave maxima
    int*   sn  = (int*)(smem + NPTS + 2 * NWAVE);  // [2][NWAVE]

    const int b   = blockIdx.x;
    const int tid = threadIdx.x;
    const float* Xp = xyz + (size_t)b * 3 * NPTS;
    const float* Yp = Xp + NPTS;
    const float* Zp = Xp + 2 * NPTS;

    float xs[PT], ys[PT], ds[PT];
#pragma unroll
    for (int j = 0; j < PT; ++j) {
        const int n = tid + j * TPB;         // interleaved: coalesced + 2-way LDS (free)
        xs[j] = Xp[n];
        ys[j] = Yp[n];
        zsh[n] = Zp[n];
        ds[j] = __builtin_inff();
    }
    if (tid == 0) idxbuf[(size_t)b * KSEL] = 0;  // idx[0] = 0
    float cx = Xp[0], cy = Yp[0], cz = Zp[0];
    __syncthreads();

    const int lane = tid & 63;
    const int wid  = tid >> 6;

    for (int t = 1; t < KSEL; ++t) {
        float bd = -__builtin_inff();
        int   bj = 0;
#pragma unroll
        for (int j = 0; j < PT; ++j) {
            const int n = tid + j * TPB;
            const float dx = xs[j] - cx;
            const float dy = ys[j] - cy;
            const float dz = zsh[n] - cz;
            // exact: ((dx*dx + dy*dy) + dz*dz), rn, no fma contraction
            const float d = __fadd_rn(__fadd_rn(__fmul_rn(dx, dx), __fmul_rn(dy, dy)),
                                      __fmul_rn(dz, dz));
            const float nd = fminf(ds[j], d);
            ds[j] = nd;
            // strict > keeps smallest j (=> smallest n for this thread); bj is a
            // 6-bit inline constant in the cndmask -> 1 fewer VALU op than full n
            const bool gt = nd > bd;
            bd = gt ? nd : bd;
            bj = gt ? j : bj;
        }
        int bn = tid + bj * TPB;
        // wave argmax: max d, tie -> min index
#pragma unroll
        for (int off = 32; off >= 1; off >>= 1) {
            const float od = __shfl_xor(bd, off);
            const int   on = __shfl_xor(bn, off);
            if (od > bd || (od == bd && on < bn)) { bd = od; bn = on; }
        }
        const int p = (t & 1) * NWAVE;
        if (lane == 0) { sd[p + wid] = bd; sn[p + wid] = bn; }
        __syncthreads();
        // all threads redundantly reduce the NWAVE wave results (broadcast reads)
        float rd = sd[p];
        int   rn = sn[p];
#pragma unroll
        for (int w = 1; w < NWAVE; ++w) {
            const float od = sd[p + w];
            const int   on = sn[p + w];
            if (od > rd || (od == rd && on < rn)) { rd = od; rn = on; }
        }
        const int rns = __builtin_amdgcn_readfirstlane(rn);
        if (tid == 0) idxbuf[(size_t)b * KSEL + t] = rns;
        // scalar (SGPR) center fetch, L2-resident
        cx = Xp[rns]; cy = Yp[rns]; cz = Zp[rns];
    }
}

__global__ void gather_kernel(const float* __restrict__ xyz,
                              const float* __restrict__ feat,
                              const int* __restrict__ idxbuf,
                              float* __restrict__ out) {
    const int SN = BATCH * 3 * KSEL;                  // 24576
    const int total = SN + BATCH * CFEAT * KSEL;      // 1073152
    const int i = blockIdx.x * blockDim.x + threadIdx.x;
    if (i >= total) return;
    if (i < SN) {
        const int b = i / (3 * KSEL);
        const int r = i - b * 3 * KSEL;
        const int c = r / KSEL;
        const int k = r - c * KSEL;
        const int n = idxbuf[b * KSEL + k];
        out[i] = xyz[((size_t)b * 3 + c) * NPTS + n];
    } else {
        const int i2 = i - SN;
        const int b = i2 / (CFEAT * KSEL);
        const int r = i2 - b * CFEAT * KSEL;
        const int c = r / KSEL;
        const int k = r - c * KSEL;
        const int n = idxbuf[b * KSEL + k];
        out[SN + i2] = feat[((size_t)b * CFEAT + c) * NPTS + n];
    }
}

extern "C" void kernel_launch(void* const* d_in, const int* in_sizes, int n_in,
                              void* d_out, int out_size, void* d_ws, size_t ws_size,
                              hipStream_t stream) {
    const float* xyz  = (const float*)d_in[0];
    const float* feat = (const float*)d_in[1];
    float* out = (float*)d_out;
    int* idxbuf = (int*)d_ws;  // BATCH*KSEL ints = 32KB

    const size_t smem_bytes = (size_t)(NPTS + 4 * NWAVE) * sizeof(float);  // ~128KB
    hipFuncSetAttribute((const void*)fps_kernel,
                        hipFuncAttributeMaxDynamicSharedMemorySize, (int)smem_bytes);

    fps_kernel<<<BATCH, TPB, smem_bytes, stream>>>(xyz, idxbuf);

    const int total = BATCH * 3 * KSEL + BATCH * CFEAT * KSEL;  // 1073152
    gather_kernel<<<(total + 255) / 256, 256, 0, stream>>>(xyz, feat, idxbuf, out);
}

// Round 3
// 4711.994 us; speedup vs baseline: 1.3722x; 1.0418x over previous
//
#include <hip/hip_runtime.h>

// Pool_FPS: furthest point sampling (B=8, N=32768, K=1024) + gather (C=128).
// FPS kernel: 1 block per batch, 1024 threads, 32 pts/thread (interleaved).
//
// ROUND-2 LESSON: the allocator pins this kernel at 128 arch VGPRs no matter
// what launch_bounds says (rounds 0-2 all report VGPR_Count=128). At PT=64
// the 192-float per-thread state spilled -> 4.9ms. Fix: design INTO the
// 128-reg budget: TPB=1024, PT=32 -> xs+ys+ds = 96 regs + temps < 128.
// z stays in dynamic LDS (128KB). 16 waves/CU also doubles latency hiding.
//
//  - exact fp32 arithmetic matching numpy/jax: d = ((dx*dx + dy*dy) + dz*dz),
//    rn ops, no fma contraction; argmax tie-break = smallest index
//    (strict > in-thread keeps smallest j; reduces compare (d, then index)).
//  - one barrier per iteration: wave argmax -> LDS slots (parity-buffered)
//    -> syncthreads -> all threads redundantly reduce 16 wave slots.
//  - center coords via readfirstlane + scalar L2-resident loads.
// Gather kernel: one thread per output element.

#define BATCH 8
#define NPTS 32768
#define KSEL 1024
#define CFEAT 128
#define TPB 1024
#define PT (NPTS / TPB)   // 32 points per thread
#define NWAVE (TPB / 64)  // 16 waves

__launch_bounds__(TPB, 4)
__global__ void fps_kernel(const float* __restrict__ xyz, int* __restrict__ idxbuf) {
    extern __shared__ float smem[];
    float* zsh = smem;                       // [NPTS] 128KB
    float* sd  = smem + NPTS;                // [2][NWAVE] parity-buffered wave maxima
    int*   sn  = (int*)(smem + NPTS + 2 * NWAVE);  // [2][NWAVE]

    const int b   = blockIdx.x;
    const int tid = threadIdx.x;
    const float* Xp = xyz + (size_t)b * 3 * NPTS;
    const float* Yp = Xp + NPTS;
    const float* Zp = Xp + 2 * NPTS;

    float xs[PT], ys[PT], ds[PT];
#pragma unroll
    for (int j = 0; j < PT; ++j) {
        const int n = tid + j * TPB;         // interleaved: coalesced global loads
        xs[j] = Xp[n];
        ys[j] = Yp[n];
        zsh[n] = Zp[n];
        ds[j] = __builtin_inff();
    }
    if (tid == 0) idxbuf[(size_t)b * KSEL] = 0;  // idx[0] = 0
    float cx = Xp[0], cy = Yp[0], cz = Zp[0];
    __syncthreads();

    const int lane = tid & 63;
    const int wid  = tid >> 6;

    for (int t = 1; t < KSEL; ++t) {
        float bd = -__builtin_inff();
        int   bj = 0;
#pragma unroll
        for (int j = 0; j < PT; ++j) {
            const int n = tid + j * TPB;
            const float dx = xs[j] - cx;
            const float dy = ys[j] - cy;
            const float dz = zsh[n] - cz;
            // exact: ((dx*dx + dy*dy) + dz*dz), rn, no fma contraction
            const float d = __fadd_rn(__fadd_rn(__fmul_rn(dx, dx), __fmul_rn(dy, dy)),
                                      __fmul_rn(dz, dz));
            const float nd = fminf(ds[j], d);
            ds[j] = nd;
            // strict > keeps smallest j (=> smallest n for this thread)
            const bool gt = nd > bd;
            bd = gt ? nd : bd;
            bj = gt ? j : bj;
        }
        int bn = tid + bj * TPB;
        // wave argmax: max d, tie -> min index
#pragma unroll
        for (int off = 32; off >= 1; off >>= 1) {
            const float od = __shfl_xor(bd, off);
            const int   on = __shfl_xor(bn, off);
            if (od > bd || (od == bd && on < bn)) { bd = od; bn = on; }
        }
        const int p = (t & 1) * NWAVE;
        if (lane == 0) { sd[p + wid] = bd; sn[p + wid] = bn; }
        __syncthreads();
        // all threads redundantly reduce the NWAVE wave results (broadcast reads)
        float rd = sd[p];
        int   rn = sn[p];
#pragma unroll
        for (int w = 1; w < NWAVE; ++w) {
            const float od = sd[p + w];
            const int   on = sn[p + w];
            if (od > rd || (od == rd && on < rn)) { rd = od; rn = on; }
        }
        const int rns = __builtin_amdgcn_readfirstlane(rn);
        if (tid == 0) idxbuf[(size_t)b * KSEL + t] = rns;
        // scalar (SGPR) center fetch, L2-resident
        cx = Xp[rns]; cy = Yp[rns]; cz = Zp[rns];
    }
}

__global__ void gather_kernel(const float* __restrict__ xyz,
                              const float* __restrict__ feat,
                              const int* __restrict__ idxbuf,
                              float* __restrict__ out) {
    const int SN = BATCH * 3 * KSEL;                  // 24576
    const int total = SN + BATCH * CFEAT * KSEL;      // 1073152
    const int i = blockIdx.x * blockDim.x + threadIdx.x;
    if (i >= total) return;
    if (i < SN) {
        const int b = i / (3 * KSEL);
        const int r = i - b * 3 * KSEL;
        const int c = r / KSEL;
        const int k = r - c * KSEL;
        const int n = idxbuf[b * KSEL + k];
        out[i] = xyz[((size_t)b * 3 + c) * NPTS + n];
    } else {
        const int i2 = i - SN;
        const int b = i2 / (CFEAT * KSEL);
        const int r = i2 - b * CFEAT * KSEL;
        const int c = r / KSEL;
        const int k = r - c * KSEL;
        const int n = idxbuf[b * KSEL + k];
        out[SN + i2] = feat[((size_t)b * CFEAT + c) * NPTS + n];
    }
}

extern "C" void kernel_launch(void* const* d_in, const int* in_sizes, int n_in,
                              void* d_out, int out_size, void* d_ws, size_t ws_size,
                              hipStream_t stream) {
    const float* xyz  = (const float*)d_in[0];
    const float* feat = (const float*)d_in[1];
    float* out = (float*)d_out;
    int* idxbuf = (int*)d_ws;  // BATCH*KSEL ints = 32KB

    const size_t smem_bytes = (size_t)(NPTS + 4 * NWAVE) * sizeof(float);  // ~128KB
    hipFuncSetAttribute((const void*)fps_kernel,
                        hipFuncAttributeMaxDynamicSharedMemorySize, (int)smem_bytes);

    fps_kernel<<<BATCH, TPB, smem_bytes, stream>>>(xyz, idxbuf);

    const int total = BATCH * 3 * KSEL + BATCH * CFEAT * KSEL;  // 1073152
    gather_kernel<<<(total + 255) / 256, 256, 0, stream>>>(xyz, feat, idxbuf, out);
}